// Round 4
// baseline (150.663 us; speedup 1.0000x reference)
//
#include <hip/hip_runtime.h>

// ---- problem constants ----
#define CIN   16
#define COUTC 8
#define HIN   8
#define WINW  8
#define SST   2
#define PPD   1
#define HOUTC 16
#define WOUTC 16
#define IN_F  2304   // CIN*3*3*4*4
#define OUT_F 4608   // COUT*3*3*8*8
#define BATCH 64

// ---- gemm decomposition ----
#define OS 6          // outer K-splits (partial buffers)
#define FW 96         // f's per wave: IN_F / (OS*4 waves)
#define NSTEP (FW/4)  // 24 spline K-steps per wave
#define PF 4          // weight prefetch depth (register-rotated)

typedef __bf16 bf16x8 __attribute__((ext_vector_type(8)));
typedef float  f32x4  __attribute__((ext_vector_type(4)));

// uniform knot grid: g[t] = (t-3)*0.4 - 1
__device__ __forceinline__ float gridv(int t) {
    return (float)(t - 3) * 0.4f - 1.0f;
}

// ---------------------------------------------------------------
// prep: u = unfold(x); activations in bf16, MFMA-B-fragment order.
//   Bsb[(f*64 + b)*8 + t]        = spline basis t  (k = f*8+t)
//   Abb[((f>>3)*64 + b)*8 + f&7] = silu(u)         (k = f)
// ---------------------------------------------------------------
__global__ __launch_bounds__(256) void prep_kernel(const float* __restrict__ x,
                                                   __bf16* __restrict__ Abb,
                                                   __bf16* __restrict__ Bsb) {
    int tid = blockIdx.x * 256 + threadIdx.x;   // tid = f*64 + b
    if (tid >= IN_F * BATCH) return;
    int f = tid >> 6, b = tid & 63;
    int ckk = f >> 4, s = f & 15;
    int c = ckk / 9, r = ckk % 9;
    int ki = r / 3, kj = r % 3;
    int oh = s >> 2, ow = s & 3;
    int h = ki + oh * SST - PPD;
    int w = kj + ow * SST - PPD;
    float u = 0.0f;
    if (h >= 0 && h < HIN && w >= 0 && w < WINW)
        u = x[((b * CIN + c) * HIN + h) * WINW + w];

    Abb[((f >> 3) * 64 + b) * 8 + (f & 7)] = (__bf16)(u / (1.0f + __expf(-u)));

    // degree-3 B-spline bases (Cox-de Boor, matches reference)
    float bs[11];
#pragma unroll
    for (int t = 0; t < 11; ++t)
        bs[t] = (u >= gridv(t) && u < gridv(t + 1)) ? 1.0f : 0.0f;
#pragma unroll
    for (int k = 1; k <= 3; ++k) {
#pragma unroll
        for (int i = 0; i < 11; ++i) {
            if (i < 11 - k) {
                float g_i  = gridv(i);
                float g_ik = gridv(i + k);
                float g_i1 = gridv(i + 1);
                float g_k1 = gridv(i + k + 1);
                bs[i] = (u - g_i) / (g_ik - g_i) * bs[i]
                      + (g_k1 - u) / (g_k1 - g_i1) * bs[i + 1];
            }
        }
    }
    bf16x8 v;
#pragma unroll
    for (int t = 0; t < 8; ++t) v[t] = (__bf16)bs[t];
    *(bf16x8*)&Bsb[(size_t)(f * 64 + b) * 8] = v;
}

// ---------------------------------------------------------------
// MFMA GEMM, weights streamed fp32 -> cvt bf16 in-register.
// Depth-4 register-rotated weight prefetch (streaming pipeline), 1-step
// activation-fragment prefetch. Block: 4 waves, same 16-o tile, 4
// consecutive K-chunks, LDS-reduced. Wave: 16 o x 64 b.
// ---------------------------------------------------------------
__global__ __launch_bounds__(256, 4) void gemm_kernel(
    const float* __restrict__ Wb,    // (OUT_F, IN_F)
    const float* __restrict__ Ws,    // (OUT_F, IN_F, 8)
    const float* __restrict__ Sc,    // (OUT_F, IN_F)
    const __bf16* __restrict__ Abb,  // base B-frags
    const __bf16* __restrict__ Bsb,  // spline B-frags
    float* __restrict__ partial)     // (OS, OUT_F, 64)
{
    __shared__ f32x4 red[4 * 256];   // 16 KB

    const int tid  = threadIdx.x;
    const int lane = tid & 63;
    const int wv   = tid >> 6;
    const int ot = blockIdx.x / OS;
    const int os = blockIdx.x % OS;
    const int o0 = ot * 16;
    const int f0 = (os * 4 + wv) * FW;
    const int lr = lane & 15;        // A-row (o), B-col (b)
    const int lg = lane >> 4;        // k-group
    const int o  = o0 + lr;

    f32x4 acc0 = {0.f,0.f,0.f,0.f}, acc1 = {0.f,0.f,0.f,0.f};
    f32x4 acc2 = {0.f,0.f,0.f,0.f}, acc3 = {0.f,0.f,0.f,0.f};

    const bf16x8* Bv = (const bf16x8*)Bsb;
    const bf16x8* Av = (const bf16x8*)Abb;

    // ================= spline GEMM: 24 K-steps, 4 f's each =================
    const float* wsrow = Ws + ((size_t)o * IN_F + f0) * 8;
    const float* scrow = Sc + (size_t)o * IN_F + f0;

    // prologue: fill 4 weight slots
    float4 pw0[PF], pw1[PF];
    float  psc[PF];
#pragma unroll
    for (int q = 0; q < PF; ++q) {
        const float* p = wsrow + (size_t)(q * 4 + lg) * 8;
        pw0[q] = *(const float4*)p;
        pw1[q] = *(const float4*)(p + 4);
        psc[q] = scrow[q * 4 + lg];
    }
    // B-frag stream: step s reads bp[s*256 + j*16]
    const bf16x8* bp = Bv + (size_t)(f0 + lg) * 64 + lr;
    bf16x8 bcur[4], bnxt[4];
#pragma unroll
    for (int j = 0; j < 4; ++j) bcur[j] = bp[j * 16];
    bp += 256;

    for (int g = 0; g < NSTEP; g += PF) {
#pragma unroll
        for (int q = 0; q < PF; ++q) {
            const int s = g + q;
            // prefetch B-frags for step s+1 (tail overreads 1 step into d_ws: unused)
#pragma unroll
            for (int j = 0; j < 4; ++j) bnxt[j] = bp[j * 16];
            bp += 256;
            // convert current weight slot (fold spline_scaler)
            bf16x8 af;
            af[0] = (__bf16)(pw0[q].x * psc[q]); af[1] = (__bf16)(pw0[q].y * psc[q]);
            af[2] = (__bf16)(pw0[q].z * psc[q]); af[3] = (__bf16)(pw0[q].w * psc[q]);
            af[4] = (__bf16)(pw1[q].x * psc[q]); af[5] = (__bf16)(pw1[q].y * psc[q]);
            af[6] = (__bf16)(pw1[q].z * psc[q]); af[7] = (__bf16)(pw1[q].w * psc[q]);
            // refill slot for step s+PF (clamped: tail re-reads last step, harmless)
            {
                int sp = s + PF; if (sp > NSTEP - 1) sp = NSTEP - 1;
                const float* p = wsrow + (size_t)(sp * 4 + lg) * 8;
                pw0[q] = *(const float4*)p;
                pw1[q] = *(const float4*)(p + 4);
                psc[q] = scrow[sp * 4 + lg];
            }
            acc0 = __builtin_amdgcn_mfma_f32_16x16x32_bf16(af, bcur[0], acc0, 0, 0, 0);
            acc1 = __builtin_amdgcn_mfma_f32_16x16x32_bf16(af, bcur[1], acc1, 0, 0, 0);
            acc2 = __builtin_amdgcn_mfma_f32_16x16x32_bf16(af, bcur[2], acc2, 0, 0, 0);
            acc3 = __builtin_amdgcn_mfma_f32_16x16x32_bf16(af, bcur[3], acc3, 0, 0, 0);
#pragma unroll
            for (int j = 0; j < 4; ++j) bcur[j] = bnxt[j];
        }
    }

    // ================= base GEMM: 3 K-steps of 32 f's =================
    const float* wbrow = Wb + (size_t)o * IN_F + f0;
    const bf16x8* ap = Av + (size_t)((f0 >> 3) + lg) * 64 + lr;
#pragma unroll
    for (int s = 0; s < FW / 32; ++s) {
        float4 w0 = *(const float4*)&wbrow[s * 32 + lg * 8];
        float4 w1 = *(const float4*)&wbrow[s * 32 + lg * 8 + 4];
        bf16x8 bb0 = ap[s * 256 +  0];
        bf16x8 bb1 = ap[s * 256 + 16];
        bf16x8 bb2 = ap[s * 256 + 32];
        bf16x8 bb3 = ap[s * 256 + 48];
        bf16x8 af;
        af[0] = (__bf16)w0.x; af[1] = (__bf16)w0.y;
        af[2] = (__bf16)w0.z; af[3] = (__bf16)w0.w;
        af[4] = (__bf16)w1.x; af[5] = (__bf16)w1.y;
        af[6] = (__bf16)w1.z; af[7] = (__bf16)w1.w;
        acc0 = __builtin_amdgcn_mfma_f32_16x16x32_bf16(af, bb0, acc0, 0, 0, 0);
        acc1 = __builtin_amdgcn_mfma_f32_16x16x32_bf16(af, bb1, acc1, 0, 0, 0);
        acc2 = __builtin_amdgcn_mfma_f32_16x16x32_bf16(af, bb2, acc2, 0, 0, 0);
        acc3 = __builtin_amdgcn_mfma_f32_16x16x32_bf16(af, bb3, acc3, 0, 0, 0);
    }

    // ---- block reduce over the 4 waves' K-chunks ----
    // D layout: lane holds D[lg*4 + r][lr]
    float* red_f = (float*)red;
#pragma unroll
    for (int r = 0; r < 4; ++r) {
        int oi = lg * 4 + r;
        red_f[wv * 1024 + oi * 64 +  0 + lr] = acc0[r];
        red_f[wv * 1024 + oi * 64 + 16 + lr] = acc1[r];
        red_f[wv * 1024 + oi * 64 + 32 + lr] = acc2[r];
        red_f[wv * 1024 + oi * 64 + 48 + lr] = acc3[r];
    }
    __syncthreads();
    f32x4 s4 = red[tid] + red[256 + tid] + red[512 + tid] + red[768 + tid];
    *(f32x4*)&partial[(size_t)os * (OUT_F * 64) + ot * 1024 + tid * 4] = s4;
}

// ---------------------------------------------------------------
// fold + OS-reduce, inverted mapping: one thread per OUTPUT element,
// gathers its <=9 contributing GEMM rows. No atomics, no memset.
// ---------------------------------------------------------------
__global__ __launch_bounds__(256) void fold_kernel(const float* __restrict__ partial,
                                                   float* __restrict__ out) {
    int gid = blockIdx.x * 256 + threadIdx.x;     // 131072 = 64*8*16*16
    int b = gid & 63, p = gid >> 6;
    int w = p & 15, h = (p >> 4) & 15, c = p >> 8;
    float sum = 0.0f;
#pragma unroll
    for (int ki = 0; ki < 3; ++ki) {
        int th = h + 1 - ki;
        if (th < 0 || (th & 1) || (th >> 1) >= 8) continue;
        int oh = th >> 1;
#pragma unroll
        for (int kj = 0; kj < 3; ++kj) {
            int tw = w + 1 - kj;
            if (tw < 0 || (tw & 1) || (tw >> 1) >= 8) continue;
            int ow = tw >> 1;
            int o = ((c * 3 + ki) * 3 + kj) * 64 + oh * 8 + ow;
            const float* pp = partial + (size_t)o * 64 + b;
#pragma unroll
            for (int os = 0; os < OS; ++os)
                sum += pp[(size_t)os * (OUT_F * 64)];
        }
    }
    out[((b * COUTC + c) * HOUTC + h) * WOUTC + w] = sum;
}

extern "C" void kernel_launch(void* const* d_in, const int* in_sizes, int n_in,
                              void* d_out, int out_size, void* d_ws, size_t ws_size,
                              hipStream_t stream) {
    const float* x  = (const float*)d_in[0];
    const float* Wb = (const float*)d_in[1];
    const float* Ws = (const float*)d_in[2];
    const float* Sc = (const float*)d_in[3];
    // d_in[4] = grid, recomputed analytically (uniform knots)

    float* out = (float*)d_out;

    __bf16* Abb    = (__bf16*)d_ws;                          // IN_F*64 bf16
    __bf16* Bsb    = Abb + (size_t)IN_F * BATCH;             // IN_F*64*8 bf16
    float*  partial = (float*)(Bsb + (size_t)IN_F * BATCH * 8); // OS*OUT_F*64 f32 (7.1 MB)

    prep_kernel<<<(IN_F * BATCH + 255) / 256, 256, 0, stream>>>(x, Abb, Bsb);

    gemm_kernel<<<(OUT_F / 16) * OS, 256, 0, stream>>>(Wb, Ws, Sc, Abb, Bsb, partial);

    fold_kernel<<<(BATCH * COUTC * HOUTC * WOUTC) / 256, 256, 0, stream>>>(partial, out);
}